// Round 6
// baseline (403.708 us; speedup 1.0000x reference)
//
#include <hip/hip_runtime.h>

#define BATCH 32
#define CIN   256
#define CHALF 128
#define NPIX  3136   // 56*56
#define MPOOL 784    // 28*28
#define MPAD  896    // 784 padded to multiple of 32 (PV K-dim)

typedef __bf16 bf16;
typedef __bf16 bf16x2 __attribute__((ext_vector_type(2)));
typedef __bf16 bf16x4 __attribute__((ext_vector_type(4)));
typedef __bf16 bf16x8 __attribute__((ext_vector_type(8)));
typedef float  f32x4  __attribute__((ext_vector_type(4)));

// ---------------------------------------------------------------------------
// k_cast: W1,W2,W3 fp32 -> Wcat[512][256] bf16
// ---------------------------------------------------------------------------
__global__ __launch_bounds__(256) void k_cast(
    const float* __restrict__ W1, const float* __restrict__ W2,
    const float* __restrict__ W3, bf16* __restrict__ Wcat)
{
    int u = blockIdx.x * 256 + threadIdx.x;
    int o = u >> 6, k4 = (u & 63) * 4;
    const float* src = (o < 128) ? (W1 + o * 256)
                     : (o < 256) ? (W2 + (o - 128) * 256)
                                 : (W3 + (o - 256) * 256);
    float4 v = *(const float4*)(src + k4);
    bf16x4 w = { (bf16)v.x, (bf16)v.y, (bf16)v.z, (bf16)v.w };
    *(bf16x4*)(Wcat + o * 256 + k4) = w;
}

// ---------------------------------------------------------------------------
// k_conv (unchanged): MFMA 1x1 convs + fused 2x2 max+avg pool.
// ---------------------------------------------------------------------------
#define XS_STRIDE   528
#define SLAB_STRIDE 520

__global__ __launch_bounds__(512) void k_conv(
    const float* __restrict__ x, const bf16* __restrict__ Wcat,
    bf16* __restrict__ c2n, bf16* __restrict__ c1pT, bf16* __restrict__ c3p)
{
    const int h2 = blockIdx.x, b = blockIdx.y;
    const int t = threadIdx.x;
    const int lane = t & 63, wave = t >> 6;
    const int l15 = lane & 15, lg = lane >> 4;

    __shared__ __align__(16) unsigned char smem[59136];

    if (h2 == 0) {
        float4 z = {0.f, 0.f, 0.f, 0.f};
        float4* p1 = (float4*)(c1pT + (size_t)b * MPAD * CHALF + (size_t)MPOOL * CHALF);
        for (int u = t; u < 1792; u += 512) p1[u] = z;
        bf16* p3 = c3p + (size_t)b * CIN * MPAD + MPOOL;
        for (int u = t; u < 256 * 14; u += 512) {
            int c = u / 14, g = u % 14;
            *(float4*)((char*)(p3 + (size_t)c * MPAD) + g * 16) = z;
        }
    }

    {
        const float* xb = x + (size_t)b * CIN * NPIX + h2 * 112;
        float vv[14][4];
        #pragma unroll
        for (int i = 0; i < 14; ++i) {
            int u = t + i * 512;
            int c4 = u / 112, n = u - c4 * 112;
            const float* s = xb + (size_t)(c4 * 4) * NPIX + n;
            vv[i][0] = s[0];
            vv[i][1] = s[NPIX];
            vv[i][2] = s[2 * NPIX];
            vv[i][3] = s[3 * NPIX];
        }
        #pragma unroll
        for (int i = 0; i < 14; ++i) {
            int u = t + i * 512;
            int c4 = u / 112, n = u - c4 * 112;
            bf16x4 w = {(bf16)vv[i][0], (bf16)vv[i][1], (bf16)vv[i][2], (bf16)vv[i][3]};
            *(bf16x4*)(smem + n * XS_STRIDE + c4 * 8) = w;
        }
    }
    __syncthreads();

    f32x4 acc[4][7];
    #pragma unroll
    for (int fo = 0; fo < 4; ++fo)
        #pragma unroll
        for (int fn = 0; fn < 7; ++fn) {
            f32x4 zz = {0.f, 0.f, 0.f, 0.f};
            acc[fo][fn] = zz;
        }
    {
        const int o0 = wave * 64;
        const bf16* wbase = Wcat + (size_t)(o0 + l15) * 256 + lg * 8;
        const unsigned char* xsb = smem + l15 * XS_STRIDE + lg * 16;
        #pragma unroll
        for (int ks = 0; ks < 8; ++ks) {
            bf16x8 afr[4], bfr[7];
            #pragma unroll
            for (int fo = 0; fo < 4; ++fo)
                afr[fo] = *(const bf16x8*)(wbase + fo * 16 * 256 + ks * 32);
            #pragma unroll
            for (int fn = 0; fn < 7; ++fn)
                bfr[fn] = *(const bf16x8*)(xsb + fn * 16 * XS_STRIDE + ks * 64);
            #pragma unroll
            for (int fo = 0; fo < 4; ++fo)
                #pragma unroll
                for (int fn = 0; fn < 7; ++fn)
                    acc[fo][fn] = __builtin_amdgcn_mfma_f32_16x16x32_bf16(
                        afr[fo], bfr[fn], acc[fo][fn], 0, 0, 0);
        }
    }

    __syncthreads();
    if (wave < 4) {
        #pragma unroll
        for (int fo = 0; fo < 4; ++fo)
            #pragma unroll
            for (int fn = 0; fn < 7; ++fn) {
                int n = fn * 16 + l15;
                int ol = wave * 64 + fo * 16 + lg * 4;
                f32x4 a = acc[fo][fn];
                bf16x4 w = {(bf16)a[0], (bf16)a[1], (bf16)a[2], (bf16)a[3]};
                *(bf16x4*)(smem + n * SLAB_STRIDE + ol * 2) = w;
            }
    }
    __syncthreads();
    {
        bf16* dst = c1pT + (size_t)b * MPAD * CHALF + (size_t)h2 * 28 * CHALF;
        for (int u = t; u < 896; u += 512) {
            int w2 = u >> 5, o4 = (u & 31) * 4;
            bf16x4 r0 = *(bf16x4*)(smem + (2 * w2)      * SLAB_STRIDE + o4 * 2);
            bf16x4 r1 = *(bf16x4*)(smem + (2 * w2 + 1)  * SLAB_STRIDE + o4 * 2);
            bf16x4 r2 = *(bf16x4*)(smem + (56 + 2 * w2) * SLAB_STRIDE + o4 * 2);
            bf16x4 r3 = *(bf16x4*)(smem + (57 + 2 * w2) * SLAB_STRIDE + o4 * 2);
            bf16x4 o_;
            #pragma unroll
            for (int j = 0; j < 4; ++j) {
                float p0 = (float)r0[j], p1 = (float)r1[j];
                float p2 = (float)r2[j], p3 = (float)r3[j];
                float mx = fmaxf(fmaxf(p0, p1), fmaxf(p2, p3));
                float av = (p0 + p1 + p2 + p3) * 0.25f;
                o_[j] = (bf16)(mx + av);
            }
            *(bf16x4*)(dst + (size_t)w2 * CHALF + o4) = o_;
        }
    }
    {
        bf16* dst = c2n + (size_t)b * NPIX * CHALF + (size_t)h2 * 112 * CHALF;
        for (int u = t; u < 3584; u += 512) {
            int n = u >> 5, o4 = (u & 31) * 4;
            bf16x4 v = *(bf16x4*)(smem + n * SLAB_STRIDE + 256 + o4 * 2);
            *(bf16x4*)(dst + (size_t)n * CHALF + o4) = v;
        }
    }

    __syncthreads();
    if (wave >= 4) {
        #pragma unroll
        for (int fo = 0; fo < 4; ++fo)
            #pragma unroll
            for (int fn = 0; fn < 7; ++fn) {
                int n = fn * 16 + l15;
                int ol = (wave - 4) * 64 + fo * 16 + lg * 4;
                f32x4 a = acc[fo][fn];
                bf16x4 w = {(bf16)a[0], (bf16)a[1], (bf16)a[2], (bf16)a[3]};
                *(bf16x4*)(smem + n * SLAB_STRIDE + ol * 2) = w;
            }
    }
    __syncthreads();
    {
        bf16* dst = c3p + (size_t)b * CIN * MPAD + h2 * 28;
        for (int u = t; u < 3584; u += 512) {
            int c = u / 14, w2p = u - c * 14;
            bf16x2 o_;
            #pragma unroll
            for (int k = 0; k < 2; ++k) {
                int w2 = 2 * w2p + k;
                float p0 = (float)*(bf16*)(smem + (2 * w2)      * SLAB_STRIDE + c * 2);
                float p1 = (float)*(bf16*)(smem + (2 * w2 + 1)  * SLAB_STRIDE + c * 2);
                float p2 = (float)*(bf16*)(smem + (56 + 2 * w2) * SLAB_STRIDE + c * 2);
                float p3 = (float)*(bf16*)(smem + (57 + 2 * w2) * SLAB_STRIDE + c * 2);
                float mx = fmaxf(fmaxf(p0, p1), fmaxf(p2, p3));
                float av = (p0 + p1 + p2 + p3) * 0.25f;
                o_[k] = (bf16)(mx + av);
            }
            *(bf16x2*)(dst + (size_t)c * MPAD + 2 * w2p) = o_;
        }
    }
}

// ---------------------------------------------------------------------------
// k_attn v4: swapped-operand S^T -> in-register softmax -> single P_lds write
// -> PV with disjoint (c-quarter, m-half) waves. nt=64, 8 waves.
// S phase:  wave = (p = wave>>1 : 16-row n-frag, h = wave&1 : 448-m half)
// PV phase: wave = (cq = wave>>1 : 64-c quarter, h2 = wave&1 : 448-m half)
// LDS: P_lds [64 n][1792 B] XOR-swizzled (112 KB), overlaid later by
//      PART (64 KB partial sums) then R (66 KB epilogue); + 1 KB exchange.
// ---------------------------------------------------------------------------
__global__ __launch_bounds__(512, 2) void k_attn(
    const bf16* __restrict__ c2n,
    const bf16* __restrict__ c1pT,
    const bf16* __restrict__ c3p,
    const float* __restrict__ x,
    const float* __restrict__ gamma,
    float* __restrict__ out)
{
    const int nb = blockIdx.x, b = blockIdx.y;
    const int n0 = nb * 64;
    const int t = threadIdx.x;
    const int lane = t & 63, wave = t >> 6;
    const int l15 = lane & 15, lg = lane >> 4;
    const int p = wave >> 1, h = wave & 1;

    __shared__ __align__(16) unsigned char smem[115712];
    float* EX = (float*)(smem + 114688);          // [2][8][16]

    // ---- S^T phase: sacc[mf] = S^T[m-frag mf][n = p*16 + l15] --------------
    bf16x8 bfrS[4];     // c2 fragments (B operand, n side) — loaded once
    {
        const bf16* c2b = c2n + ((size_t)b * NPIX + n0 + p * 16 + l15) * CHALF + lg * 8;
        #pragma unroll
        for (int k = 0; k < 4; ++k)
            bfrS[k] = *(const bf16x8*)(c2b + k * 32);
    }
    f32x4 sacc[28];
    {
        const bf16* c1b = c1pT + ((size_t)b * MPAD + h * 448 + l15) * CHALF + lg * 8;
        #pragma unroll
        for (int mf = 0; mf < 28; ++mf) {
            f32x4 z = {0.f, 0.f, 0.f, 0.f};
            sacc[mf] = z;
            bf16x8 af[4];
            #pragma unroll
            for (int k = 0; k < 4; ++k)
                af[k] = *(const bf16x8*)(c1b + (size_t)mf * 16 * CHALF + k * 32);
            #pragma unroll
            for (int k = 0; k < 4; ++k)
                sacc[mf] = __builtin_amdgcn_mfma_f32_16x16x32_bf16(af[k], bfrS[k], sacc[mf], 0, 0, 0);
        }
    }

    // ---- in-register softmax over m (lane owns full m-half of one n) -------
    // valid frags: h==0 -> all 28; h==1 -> mf<21 (m>=784 is pad)
    float mx = -1e30f;
    #pragma unroll
    for (int mf = 0; mf < 28; ++mf) {
        if (h == 0 || mf < 21) {
            mx = fmaxf(mx, fmaxf(fmaxf(sacc[mf][0], sacc[mf][1]),
                                 fmaxf(sacc[mf][2], sacc[mf][3])));
        }
    }
    mx = fmaxf(mx, __shfl_xor(mx, 16));
    mx = fmaxf(mx, __shfl_xor(mx, 32));
    if (lane < 16) EX[wave * 16 + l15] = mx;
    __syncthreads();
    mx = fmaxf(mx, EX[(wave ^ 1) * 16 + l15]);

    float s = 0.f;
    #pragma unroll
    for (int mf = 0; mf < 28; ++mf) {
        if (h == 0 || mf < 21) {
            #pragma unroll
            for (int r = 0; r < 4; ++r) {
                float e = __expf(sacc[mf][r] - mx);
                sacc[mf][r] = e;
                s += e;
            }
        }
    }
    s += __shfl_xor(s, 16);
    s += __shfl_xor(s, 32);
    if (lane < 16) EX[128 + wave * 16 + l15] = s;
    __syncthreads();
    s += EX[128 + (wave ^ 1) * 16 + l15];
    const float ri = 1.f / s;

    // ---- pack P to bf16, single swizzled b64 store per frag ----------------
    {
        const unsigned sw = (unsigned)((l15 & 7) << 4);
        const unsigned rowb = (unsigned)((p * 16 + l15) * 1792);
        #pragma unroll
        for (int mf = 0; mf < 28; ++mf) {
            bf16x4 w;
            if (h == 0 || mf < 21) {
                w = bf16x4{ (bf16)(sacc[mf][0] * ri), (bf16)(sacc[mf][1] * ri),
                            (bf16)(sacc[mf][2] * ri), (bf16)(sacc[mf][3] * ri) };
            } else {
                w = bf16x4{ (bf16)0.f, (bf16)0.f, (bf16)0.f, (bf16)0.f };
            }
            unsigned byte = rowb + (unsigned)(h * 896 + mf * 32 + lg * 8);
            *(bf16x4*)(smem + (byte ^ sw)) = w;
        }
    }
    __syncthreads();

    // ---- PV: refined^T[c][n] = sum_m V^T[c][m] * P^T[m][n] -----------------
    const int cq = wave >> 1, h2 = wave & 1;
    f32x4 acc2[4][4];   // [cf][nf]
    #pragma unroll
    for (int cf = 0; cf < 4; ++cf)
        #pragma unroll
        for (int nf = 0; nf < 4; ++nf) {
            f32x4 z = {0.f, 0.f, 0.f, 0.f};
            acc2[cf][nf] = z;
        }
    {
        const bf16* c3w = c3p + ((size_t)b * CIN + cq * 64 + l15) * MPAD + h2 * 448 + lg * 8;
        #pragma unroll
        for (int ks = 0; ks < 14; ++ks) {
            bf16x8 pb[4];
            #pragma unroll
            for (int nf = 0; nf < 4; ++nf) {
                int n = nf * 16 + l15;
                unsigned byte = (unsigned)(n * 1792 + h2 * 896 + ks * 64 + lg * 16)
                              ^ (unsigned)((n & 7) << 4);
                pb[nf] = *(const bf16x8*)(smem + byte);
            }
            #pragma unroll
            for (int cf = 0; cf < 4; ++cf) {
                bf16x8 av = *(const bf16x8*)(c3w + (size_t)cf * 16 * MPAD + ks * 32);
                #pragma unroll
                for (int nf = 0; nf < 4; ++nf)
                    acc2[cf][nf] = __builtin_amdgcn_mfma_f32_16x16x32_bf16(av, pb[nf], acc2[cf][nf], 0, 0, 0);
            }
        }
    }

    // ---- cross-half partial reduction via LDS ------------------------------
    __syncthreads();    // all P_lds reads complete
    if (h2 == 1) {
        f32x4* dst = (f32x4*)smem + (size_t)cq * 1024 + lane;
        #pragma unroll
        for (int cf = 0; cf < 4; ++cf)
            #pragma unroll
            for (int nf = 0; nf < 4; ++nf)
                dst[(cf * 4 + nf) * 64] = acc2[cf][nf];
    }
    __syncthreads();
    if (h2 == 0) {
        const f32x4* src = (const f32x4*)smem + (size_t)cq * 1024 + lane;
        #pragma unroll
        for (int cf = 0; cf < 4; ++cf)
            #pragma unroll
            for (int nf = 0; nf < 4; ++nf)
                acc2[cf][nf] += src[(cf * 4 + nf) * 64];
    }
    __syncthreads();

    // ---- epilogue: R[n][c] in LDS, coalesced out = g*refined + x -----------
    float* R = (float*)smem;    // [64][257]
    if (h2 == 0) {
        #pragma unroll
        for (int cf = 0; cf < 4; ++cf)
            #pragma unroll
            for (int nf = 0; nf < 4; ++nf) {
                int c = cq * 64 + cf * 16 + lg * 4;
                #pragma unroll
                for (int r = 0; r < 4; ++r)
                    R[(nf * 16 + l15) * 257 + c + r] = acc2[cf][nf][r];
            }
    }
    __syncthreads();
    const float g = gamma[0];
    const float* xb = x + (size_t)b * CIN * NPIX + n0;
    float* ob = out + (size_t)b * CIN * NPIX + n0;
    #pragma unroll 4
    for (int i = 0; i < 32; ++i) {
        int idx = t + i * 512;                  // 256 c x 64 n
        int c = idx >> 6, nn = idx & 63;
        size_t off = (size_t)c * NPIX + nn;
        ob[off] = g * R[nn * 257 + c] + xb[off];
    }
}

extern "C" void kernel_launch(void* const* d_in, const int* in_sizes, int n_in,
                              void* d_out, int out_size, void* d_ws, size_t ws_size,
                              hipStream_t stream) {
    const float* x     = (const float*)d_in[0];
    const float* W1    = (const float*)d_in[1];
    const float* W2    = (const float*)d_in[2];
    const float* W3    = (const float*)d_in[3];
    const float* gamma = (const float*)d_in[4];
    float* out = (float*)d_out;

    bf16* ws   = (bf16*)d_ws;
    bf16* Wcat = ws;                                       // 512*256
    bf16* c2n  = Wcat + (size_t)512 * 256;                 // 32*3136*128
    bf16* c1pT = c2n + (size_t)BATCH * NPIX * CHALF;       // 32*896*128
    bf16* c3p  = c1pT + (size_t)BATCH * MPAD * CHALF;      // 32*256*896

    k_cast<<<128, 256, 0, stream>>>(W1, W2, W3, Wcat);
    k_conv<<<dim3(28, BATCH), 512, 0, stream>>>(x, Wcat, c2n, c1pT, c3p);
    k_attn<<<dim3(49, BATCH), 512, 0, stream>>>(c2n, c1pT, c3p, x, gamma, out);
}